// Round 17
// baseline (116.220 us; speedup 1.0000x reference)
//
#include <hip/hip_runtime.h>
#include <hip/hip_bf16.h>

// GPT2 attention: B=8, T=1024, D=768, H=12, hd=64. fp32 in/out, bf16 MFMA compute.
#define B_ 8
#define T_ 1024
#define D_ 768
#define NH 12
#define HD 64

typedef __bf16 bf16x8 __attribute__((ext_vector_type(8)));
typedef __bf16 bf16x4 __attribute__((ext_vector_type(4)));
typedef float f32x4 __attribute__((ext_vector_type(4)));
typedef short s16x4 __attribute__((ext_vector_type(4)));

__device__ __forceinline__ float fast_exp2(float x) {
  return __builtin_amdgcn_exp2f(x);
}

__device__ __forceinline__ f32x4 mfma32(bf16x8 a, bf16x8 b, f32x4 c) {
  return __builtin_amdgcn_mfma_f32_16x16x32_bf16(a, b, c, 0, 0, 0);
}

__device__ __forceinline__ f32x4 mfma16(bf16x4 a, bf16x4 b, f32x4 c) {
  union U { bf16x4 h; s16x4 s; };
  U ua; ua.h = a;
  U ub; ub.h = b;
  return __builtin_amdgcn_mfma_f32_16x16x16bf16_1k(ua.s, ub.s, c, 0, 0, 0);
}

// async global->LDS, 16B per lane; LDS dest = wave-uniform base + lane*16
__device__ __forceinline__ void gload_lds16(const void* g, void* l) {
  __builtin_amdgcn_global_load_lds((const __attribute__((address_space(1))) unsigned int*)g,
                                   (__attribute__((address_space(3))) unsigned int*)l, 16, 0, 0);
}

// ---------------- merged prep: x->bf16 + both W transposes (one launch) ----------------
__global__ void prep_kernel(const float* __restrict__ x, __bf16* __restrict__ xb,
                            const float* __restrict__ W_attn, __bf16* __restrict__ WaT,
                            const float* __restrict__ W_proj, __bf16* __restrict__ WpT) {
  int bid = blockIdx.x;
  int tid = threadIdx.x;
  if (bid < 3072) {
    int i = bid * 256 + tid;
    const float4* xf = (const float4*)x;
    float4 a = xf[i * 2], b = xf[i * 2 + 1];
    bf16x8 v;
    v[0] = (__bf16)a.x; v[1] = (__bf16)a.y; v[2] = (__bf16)a.z; v[3] = (__bf16)a.w;
    v[4] = (__bf16)b.x; v[5] = (__bf16)b.y; v[6] = (__bf16)b.z; v[7] = (__bf16)b.w;
    *(bf16x8*)&xb[(size_t)i * 8] = v;
    return;
  }
  __shared__ float tile[32][33];
  const float* W;
  __bf16* WT;
  int K = 768, N, n0, k0;
  if (bid < 4800) {
    int i = bid - 3072;
    W = W_attn; WT = WaT; N = 2304;
    n0 = (i % 72) * 32; k0 = (i / 72) * 32;
  } else {
    int i = bid - 4800;
    W = W_proj; WT = WpT; N = 768;
    n0 = (i % 24) * 32; k0 = (i / 24) * 32;
  }
  int col = tid & 31, r0 = tid >> 5;
#pragma unroll
  for (int p = 0; p < 4; p++) {
    int r = r0 + p * 8;
    tile[r][col] = W[(size_t)(k0 + r) * N + n0 + col];
  }
  __syncthreads();
#pragma unroll
  for (int p = 0; p < 4; p++) {
    int r = r0 + p * 8;
    WT[(size_t)(n0 + r) * K + k0 + col] = (__bf16)tile[col][r];
  }
}

// ---------------- QKV GEMM: 128x128, r12 dbuf loop (best-measured, unchanged) ----------------
__global__ __launch_bounds__(256) void gemm_qkv(const __bf16* __restrict__ A,
                                                const __bf16* __restrict__ BT,
                                                const float* __restrict__ bias,
                                                __bf16* __restrict__ Cout,
                                                __bf16* __restrict__ VT,
                                                int M, int N, int K, int nbx) {
  __shared__ __align__(16) __bf16 Asm[2][128 * 64];
  __shared__ __align__(16) __bf16 Bsm[2][128 * 64];
  int tid = threadIdx.x;
  int wave = tid >> 6, lane = tid & 63, g = lane >> 4, l15 = lane & 15;
  int wr = wave >> 1, wc = wave & 1;

  int wg = blockIdx.x;
  int cpx = gridDim.x >> 3;
  int wg2 = (wg & 7) * cpx + (wg >> 3);
  int bx = wg2 % nbx, by = wg2 / nbx;
  int m0 = by * 128, n0 = bx * 128;

  int srow = tid >> 3;
  int cc = (tid & 7) ^ ((tid >> 3) & 7);
  const __bf16* Ag = A + (size_t)(m0 + srow) * K + cc * 8;
  const __bf16* Bg = BT + (size_t)(n0 + srow) * K + cc * 8;

  auto stage = [&](int kt, int bf) {
#pragma unroll
    for (int i = 0; i < 4; i++) {
      gload_lds16(Ag + (size_t)(i * 32) * K + kt * 64, &Asm[bf][wave * 512 + i * 2048]);
      gload_lds16(Bg + (size_t)(i * 32) * K + kt * 64, &Bsm[bf][wave * 512 + i * 2048]);
    }
  };

  f32x4 zz = {0.0f, 0.0f, 0.0f, 0.0f};
  f32x4 acc[4][4];
#pragma unroll
  for (int m = 0; m < 4; m++)
#pragma unroll
    for (int n = 0; n < 4; n++) acc[m][n] = zz;

  int nk = K >> 6;
  int swr = l15 & 7;

  stage(0, 0);
  __syncthreads();

  int cur = 0;
  for (int kt = 0; kt < nk; kt++) {
    if (kt + 1 < nk) stage(kt + 1, cur ^ 1);  // async, overlaps compute below
#pragma unroll
    for (int ks = 0; ks < 2; ks++) {
      bf16x8 af[4], bfr[4];
#pragma unroll
      for (int m = 0; m < 4; m++) {
        int row = wr * 64 + m * 16 + l15;
        af[m] = *(const bf16x8*)&Asm[cur][row * 64 + ((ks * 4 + g) ^ swr) * 8];
      }
#pragma unroll
      for (int n = 0; n < 4; n++) {
        int row = wc * 64 + n * 16 + l15;
        bfr[n] = *(const bf16x8*)&Bsm[cur][row * 64 + ((ks * 4 + g) ^ swr) * 8];
      }
#pragma unroll
      for (int m = 0; m < 4; m++)
#pragma unroll
        for (int n = 0; n < 4; n++)
          acc[m][n] = __builtin_amdgcn_mfma_f32_16x16x32_bf16(af[m], bfr[n], acc[m][n], 0, 0, 0);
    }
    __syncthreads();  // reads of cur done; kt+1 DMA drained
    cur ^= 1;
  }
#pragma unroll
  for (int n = 0; n < 4; n++) {
    int gcol = n0 + wc * 64 + n * 16 + l15;
    float bv = bias[gcol];
#pragma unroll
    for (int m = 0; m < 4; m++) {
      int grow0 = m0 + wr * 64 + m * 16 + g * 4;
      float v0 = acc[m][n][0] + bv, v1 = acc[m][n][1] + bv;
      float v2 = acc[m][n][2] + bv, v3 = acc[m][n][3] + bv;
      if (gcol < 2 * D_) {
        Cout[(size_t)(grow0 + 0) * N + gcol] = (__bf16)v0;
        Cout[(size_t)(grow0 + 1) * N + gcol] = (__bf16)v1;
        Cout[(size_t)(grow0 + 2) * N + gcol] = (__bf16)v2;
        Cout[(size_t)(grow0 + 3) * N + gcol] = (__bf16)v3;
      } else {
        int hh = (gcol - 2 * D_) >> 6, dd = (gcol - 2 * D_) & 63;
        int bb = grow0 >> 10, tt = grow0 & 1023;
        bf16x4 sv = {(__bf16)v0, (__bf16)v1, (__bf16)v2, (__bf16)v3};
        *(bf16x4*)&VT[((size_t)(bb * NH + hh) * HD + dd) * T_ + tt] = sv;
      }
    }
  }
}

// ---------------- proj GEMM: 128x64 tile (r15, unchanged) ----------------
__global__ __launch_bounds__(256) void gemm_proj(const __bf16* __restrict__ A,
                                                 const __bf16* __restrict__ BT,
                                                 const float* __restrict__ bias,
                                                 float* __restrict__ Cout,
                                                 int M, int N, int K, int nbx) {
  __shared__ __align__(16) __bf16 Asm[2][128 * 64];
  __shared__ __align__(16) __bf16 Bsm[2][64 * 64];
  int tid = threadIdx.x;
  int wave = tid >> 6, lane = tid & 63, g = lane >> 4, l15 = lane & 15;

  int wg = blockIdx.x;
  int cpx = gridDim.x >> 3;
  int wg2 = (wg & 7) * cpx + (wg >> 3);
  int bx = wg2 % nbx, by = wg2 / nbx;
  int m0 = by * 128, n0 = bx * 64;

  int srow = tid >> 3;
  int cc = (tid & 7) ^ ((tid >> 3) & 7);
  const __bf16* Ag = A + (size_t)(m0 + srow) * K + cc * 8;
  const __bf16* Bg = BT + (size_t)(n0 + srow) * K + cc * 8;

  auto stage = [&](int kt, int bf) {
#pragma unroll
    for (int i = 0; i < 4; i++)
      gload_lds16(Ag + (size_t)(i * 32) * K + kt * 64, &Asm[bf][wave * 512 + i * 2048]);
#pragma unroll
    for (int i = 0; i < 2; i++)
      gload_lds16(Bg + (size_t)(i * 32) * K + kt * 64, &Bsm[bf][wave * 512 + i * 2048]);
  };

  f32x4 zz = {0.0f, 0.0f, 0.0f, 0.0f};
  f32x4 acc[2][4];
#pragma unroll
  for (int m = 0; m < 2; m++)
#pragma unroll
    for (int n = 0; n < 4; n++) acc[m][n] = zz;

  int nk = K >> 6;
  int swr = l15 & 7;

  stage(0, 0);
  __syncthreads();

  int cur = 0;
  for (int kt = 0; kt < nk; kt++) {
    if (kt + 1 < nk) stage(kt + 1, cur ^ 1);
#pragma unroll
    for (int ks = 0; ks < 2; ks++) {
      bf16x8 af[2], bfr[4];
#pragma unroll
      for (int m = 0; m < 2; m++) {
        int row = wave * 32 + m * 16 + l15;
        af[m] = *(const bf16x8*)&Asm[cur][row * 64 + ((ks * 4 + g) ^ swr) * 8];
      }
#pragma unroll
      for (int n = 0; n < 4; n++) {
        int row = n * 16 + l15;
        bfr[n] = *(const bf16x8*)&Bsm[cur][row * 64 + ((ks * 4 + g) ^ swr) * 8];
      }
#pragma unroll
      for (int m = 0; m < 2; m++)
#pragma unroll
        for (int n = 0; n < 4; n++)
          acc[m][n] = __builtin_amdgcn_mfma_f32_16x16x32_bf16(af[m], bfr[n], acc[m][n], 0, 0, 0);
    }
    __syncthreads();
    cur ^= 1;
  }
#pragma unroll
  for (int n = 0; n < 4; n++) {
    int gcol = n0 + n * 16 + l15;
    float bv = bias[gcol];
#pragma unroll
    for (int m = 0; m < 2; m++) {
      int grow0 = m0 + wave * 32 + m * 16 + g * 4;
#pragma unroll
      for (int r = 0; r < 4; r++)
        Cout[(size_t)(grow0 + r) * N + gcol] = acc[m][n][r] + bv;
    }
  }
}

// ---------------- causal flash attention: wave = 32 q-rows (two 16-row subtiles) ----------------
// Block = 128 q-rows (4 waves x 32), grid (96, 8) = 768 blocks = exactly
// 3 blocks/CU all-resident. Per staged K/V tile the compute doubles vs r16;
// barriers + staging per q-row halve. Subtiles run SEQUENTIALLY (live VGPR
// state ~150, no spill). Causal bonus: the low subtile is fully masked at
// kt == nkt-1 (keys >= qb*128+64 > all its rows) -> skipped (wave-uniform).
// Defer-max (T13), setprio (T5), XOR swizzle, stagger — carried from r16.
#define SCL 0.1803368801111204f  // 0.125 * log2(e)

__global__ __launch_bounds__(256, 3) void attn_kernel(const __bf16* __restrict__ qkv,
                                                      const __bf16* __restrict__ VT,
                                                      __bf16* __restrict__ attn_out) {
  __shared__ __align__(16) __bf16 sm[2][2][4096];  // [buf][0=K,1=V][64x64]
  int tid = threadIdx.x;
  int wave = tid >> 6, lane = tid & 63, g = lane >> 4, l15 = lane & 15;
  int bh = blockIdx.x;
  int b = bh / NH, h = bh % NH;
  int qb = 7 - blockIdx.y;  // heavy first
  int q0a = qb * 128 + wave * 16;  // low subtile rows
  int q0b = q0a + 64;              // high subtile rows
  int nkt = 2 * qb + 2;
  int s0 = (bh + qb) % nkt;

  int kr = tid >> 3, cc = (tid & 7) ^ ((tid >> 3) & 7);
  const __bf16* Kst = qkv + (size_t)(b * T_ + kr) * (3 * D_) + D_ + h * HD + cc * 8;
  const __bf16* Vst = VT + ((size_t)bh * HD + kr) * T_ + cc * 8;
  __bf16* ldsK0 = &sm[0][0][wave * 512];
  __bf16* ldsV0 = &sm[0][1][wave * 512];
  __bf16* ldsK1 = &sm[1][0][wave * 512];
  __bf16* ldsV1 = &sm[1][1][wave * 512];

  auto stage = [&](int t, int bf) {
    size_t ko = (size_t)(t * 64) * (3 * D_);
    int vo = t * 64;
    __bf16* lk = bf ? ldsK1 : ldsK0;
    __bf16* lv = bf ? ldsV1 : ldsV0;
    gload_lds16(Kst + ko, lk);
    gload_lds16(Kst + ko + (size_t)32 * (3 * D_), lk + 2048);
    gload_lds16(Vst + vo, lv);
    gload_lds16(Vst + vo + 32 * T_, lv + 2048);
  };

  const __bf16* Qpa = qkv + (size_t)(b * T_ + q0a + l15) * (3 * D_) + h * HD;
  const __bf16* Qpb = Qpa + (size_t)64 * (3 * D_);
  bf16x8 qa_lo = *(const bf16x8*)(Qpa + g * 8);
  bf16x8 qa_hi = *(const bf16x8*)(Qpa + 32 + g * 8);
  bf16x8 qb_lo = *(const bf16x8*)(Qpb + g * 8);
  bf16x8 qb_hi = *(const bf16x8*)(Qpb + 32 + g * 8);

  f32x4 zz = {0.0f, 0.0f, 0.0f, 0.0f};
  f32x4 o_a[4], o_b[4];
#pragma unroll
  for (int dq = 0; dq < 4; dq++) { o_a[dq] = zz; o_b[dq] = zz; }
  float m_a = -1e30f, l_a = 0.0f, m_b = -1e30f, l_b = 0.0f;
  int sw = l15 & 7;
  int clo = (g ^ sw) * 8;
  int chi = ((4 + g) ^ sw) * 8;
  int vhalf = (g & 1) * 4;
  int vc = g >> 1;
  int thr = wave * 16 + l15;  // relative causal threshold (same for both subtiles)

  // per-subtile step body (kt uniform per block -> all branches wave-uniform)
  auto tile_body = [&](int masked, const __bf16* Kb, const __bf16* Vb,
                       bf16x8 qlo, bf16x8 qhi, float& m, float& l, f32x4* o) {
    f32x4 s[4];
    __builtin_amdgcn_s_setprio(1);
#pragma unroll
    for (int kg = 0; kg < 4; kg++) {
      int rb = (kg * 16 + l15) * 64;
      bf16x8 kf = *(const bf16x8*)(Kb + rb + clo);
      bf16x8 kh = *(const bf16x8*)(Kb + rb + chi);
      s[kg] = mfma32(kf, qlo, zz);
      s[kg] = mfma32(kh, qhi, s[kg]);
    }
    __builtin_amdgcn_s_setprio(0);
    float v[16];
#pragma unroll
    for (int kg = 0; kg < 4; kg++)
#pragma unroll
      for (int r = 0; r < 4; r++) v[kg * 4 + r] = s[kg][r] * SCL;
    if (masked) {
#pragma unroll
      for (int kg = 0; kg < 4; kg++)
#pragma unroll
        for (int r = 0; r < 4; r++)
          if (kg * 16 + g * 4 + r > thr) v[kg * 4 + r] = -1e30f;
    }
    float m0a = fmaxf(fmaxf(v[0], v[1]), fmaxf(v[2], v[3]));
    float m1a = fmaxf(fmaxf(v[4], v[5]), fmaxf(v[6], v[7]));
    float m2a = fmaxf(fmaxf(v[8], v[9]), fmaxf(v[10], v[11]));
    float m3a = fmaxf(fmaxf(v[12], v[13]), fmaxf(v[14], v[15]));
    float mx = fmaxf(fmaxf(m0a, m1a), fmaxf(m2a, m3a));
    mx = fmaxf(mx, __shfl_xor(mx, 16));
    mx = fmaxf(mx, __shfl_xor(mx, 32));
    if (!__all(mx <= m + 8.0f)) {  // T13 defer-max
      float mnew = fmaxf(m, mx);
      float corr = fast_exp2(m - mnew);
#pragma unroll
      for (int dq = 0; dq < 4; dq++) o[dq] *= corr;
      l *= corr;
      m = mnew;
    }
    float p[16], sum = 0.0f;
#pragma unroll
    for (int i2 = 0; i2 < 16; i2++) { p[i2] = fast_exp2(v[i2] - m); sum += p[i2]; }
    sum += __shfl_xor(sum, 16);
    sum += __shfl_xor(sum, 32);
    l += sum;
    bf16x4 pk[4];
#pragma unroll
    for (int kg = 0; kg < 4; kg++) {
      pk[kg][0] = (__bf16)p[kg * 4 + 0];
      pk[kg][1] = (__bf16)p[kg * 4 + 1];
      pk[kg][2] = (__bf16)p[kg * 4 + 2];
      pk[kg][3] = (__bf16)p[kg * 4 + 3];
    }
    __builtin_amdgcn_s_setprio(1);
#pragma unroll
    for (int dq = 0; dq < 4; dq++) {
      int drow = (dq * 16 + l15) * 64;
#pragma unroll
      for (int ks = 0; ks < 4; ks++) {
        bf16x4 vf = *(const bf16x4*)(Vb + drow + ((ks * 2 + vc) ^ sw) * 8 + vhalf);
        o[dq] = mfma16(vf, pk[ks], o[dq]);
      }
    }
    __builtin_amdgcn_s_setprio(0);
  };

  stage(s0, 0);
  __syncthreads();

  int cur = 0;
  for (int i = 0; i < nkt; i++) {
    int kt = s0 + i;
    if (kt >= nkt) kt -= nkt;
    if (i + 1 < nkt) stage(kt + 1 == nkt ? 0 : kt + 1, cur ^ 1);

    const __bf16* Kb = &sm[cur][0][0];
    const __bf16* Vb = &sm[cur][1][0];
    if (kt != nkt - 1)  // low subtile: fully masked at the last key tile -> skip
      tile_body(kt == nkt - 2, Kb, Vb, qa_lo, qa_hi, m_a, l_a, o_a);
    tile_body(kt == nkt - 1, Kb, Vb, qb_lo, qb_hi, m_b, l_b, o_b);

    __syncthreads();
    cur ^= 1;
  }

  float invla = 1.0f / l_a, invlb = 1.0f / l_b;
  __bf16* outA = attn_out + (size_t)(b * T_ + q0a + l15) * D_ + h * HD + g * 4;
  __bf16* outB = outA + (size_t)64 * D_;
#pragma unroll
  for (int dq = 0; dq < 4; dq++) {
    bf16x4 sa = {(__bf16)(o_a[dq][0] * invla), (__bf16)(o_a[dq][1] * invla),
                 (__bf16)(o_a[dq][2] * invla), (__bf16)(o_a[dq][3] * invla)};
    bf16x4 sb = {(__bf16)(o_b[dq][0] * invlb), (__bf16)(o_b[dq][1] * invlb),
                 (__bf16)(o_b[dq][2] * invlb), (__bf16)(o_b[dq][3] * invlb)};
    *(bf16x4*)(outA + dq * 16) = sa;
    *(bf16x4*)(outB + dq * 16) = sb;
  }
}

extern "C" void kernel_launch(void* const* d_in, const int* in_sizes, int n_in,
                              void* d_out, int out_size, void* d_ws, size_t ws_size,
                              hipStream_t stream) {
  (void)in_sizes; (void)n_in; (void)out_size; (void)ws_size;
  const float* x = (const float*)d_in[0];
  const float* W_attn = (const float*)d_in[1];
  const float* b_attn = (const float*)d_in[2];
  const float* W_proj = (const float*)d_in[3];
  const float* b_proj = (const float*)d_in[4];

  char* ws = (char*)d_ws;
  __bf16* xb  = (__bf16*)(ws + 0);          // 8192*768*2        = 12,582,912
  __bf16* WaT = (__bf16*)(ws + 12582912);   // 2304*768*2        =  3,538,944
  __bf16* WpT = (__bf16*)(ws + 16121856);   // 768*768*2         =  1,179,648
  __bf16* qkv = (__bf16*)(ws + 17301504);   // 8192*2304*2       = 37,748,736
  __bf16* VTb = (__bf16*)(ws + 55050240);   // 96*64*1024*2      = 12,582,912
  __bf16* att = (__bf16*)(ws + 67633152);   // 8192*768*2        = 12,582,912

  prep_kernel<<<dim3(5376), 256, 0, stream>>>(x, xb, W_attn, WaT, W_proj, WpT);
  gemm_qkv<<<dim3(1152), 256, 0, stream>>>(xb, WaT, b_attn, qkv, VTb, 8192, 2304, 768, 18);
  attn_kernel<<<dim3(96, 8), 256, 0, stream>>>(qkv, VTb, att);
  gemm_proj<<<dim3(768), 256, 0, stream>>>(att, WpT, b_proj, (float*)d_out, 8192, 768, 768, 12);
}

// Round 18
// 111.716 us; speedup vs baseline: 1.0403x; 1.0403x over previous
//
#include <hip/hip_runtime.h>
#include <hip/hip_bf16.h>

// GPT2 attention: B=8, T=1024, D=768, H=12, hd=64. fp32 in/out, bf16 MFMA compute.
#define B_ 8
#define T_ 1024
#define D_ 768
#define NH 12
#define HD 64

typedef __bf16 bf16x8 __attribute__((ext_vector_type(8)));
typedef __bf16 bf16x4 __attribute__((ext_vector_type(4)));
typedef float f32x4 __attribute__((ext_vector_type(4)));
typedef short s16x4 __attribute__((ext_vector_type(4)));

__device__ __forceinline__ float fast_exp2(float x) {
  return __builtin_amdgcn_exp2f(x);
}

__device__ __forceinline__ f32x4 mfma32(bf16x8 a, bf16x8 b, f32x4 c) {
  return __builtin_amdgcn_mfma_f32_16x16x32_bf16(a, b, c, 0, 0, 0);
}

__device__ __forceinline__ f32x4 mfma16(bf16x4 a, bf16x4 b, f32x4 c) {
  union U { bf16x4 h; s16x4 s; };
  U ua; ua.h = a;
  U ub; ub.h = b;
  return __builtin_amdgcn_mfma_f32_16x16x16bf16_1k(ua.s, ub.s, c, 0, 0, 0);
}

// async global->LDS, 16B per lane; LDS dest = wave-uniform base + lane*16
__device__ __forceinline__ void gload_lds16(const void* g, void* l) {
  __builtin_amdgcn_global_load_lds((const __attribute__((address_space(1))) unsigned int*)g,
                                   (__attribute__((address_space(3))) unsigned int*)l, 16, 0, 0);
}

// ---------------- merged prep: x->bf16 + both W transposes (one launch) ----------------
__global__ void prep_kernel(const float* __restrict__ x, __bf16* __restrict__ xb,
                            const float* __restrict__ W_attn, __bf16* __restrict__ WaT,
                            const float* __restrict__ W_proj, __bf16* __restrict__ WpT) {
  int bid = blockIdx.x;
  int tid = threadIdx.x;
  if (bid < 3072) {
    int i = bid * 256 + tid;
    const float4* xf = (const float4*)x;
    float4 a = xf[i * 2], b = xf[i * 2 + 1];
    bf16x8 v;
    v[0] = (__bf16)a.x; v[1] = (__bf16)a.y; v[2] = (__bf16)a.z; v[3] = (__bf16)a.w;
    v[4] = (__bf16)b.x; v[5] = (__bf16)b.y; v[6] = (__bf16)b.z; v[7] = (__bf16)b.w;
    *(bf16x8*)&xb[(size_t)i * 8] = v;
    return;
  }
  __shared__ float tile[32][33];
  const float* W;
  __bf16* WT;
  int K = 768, N, n0, k0;
  if (bid < 4800) {
    int i = bid - 3072;
    W = W_attn; WT = WaT; N = 2304;
    n0 = (i % 72) * 32; k0 = (i / 72) * 32;
  } else {
    int i = bid - 4800;
    W = W_proj; WT = WpT; N = 768;
    n0 = (i % 24) * 32; k0 = (i / 24) * 32;
  }
  int col = tid & 31, r0 = tid >> 5;
#pragma unroll
  for (int p = 0; p < 4; p++) {
    int r = r0 + p * 8;
    tile[r][col] = W[(size_t)(k0 + r) * N + n0 + col];
  }
  __syncthreads();
#pragma unroll
  for (int p = 0; p < 4; p++) {
    int r = r0 + p * 8;
    WT[(size_t)(n0 + r) * K + k0 + col] = (__bf16)tile[col][r];
  }
}

// ---------------- QKV GEMM: 128x128, r12 dbuf loop (best-measured) ----------------
// 4 waves (2x2), BK=64, gload_lds width-16, double-buffered LDS (64KB, 2 blk/CU),
// stage(kt+1) at step top overlapping compute, one __syncthreads per step.
// Both-sides XOR swizzle -> 0 conflicts. T1 XCD swizzle (grid%8==0).
// Epilogue: Q,K -> qkv; V -> VT[bh][d][t] (vtrepack fused).
__global__ __launch_bounds__(256) void gemm_qkv(const __bf16* __restrict__ A,
                                                const __bf16* __restrict__ BT,
                                                const float* __restrict__ bias,
                                                __bf16* __restrict__ Cout,
                                                __bf16* __restrict__ VT,
                                                int M, int N, int K, int nbx) {
  __shared__ __align__(16) __bf16 Asm[2][128 * 64];
  __shared__ __align__(16) __bf16 Bsm[2][128 * 64];
  int tid = threadIdx.x;
  int wave = tid >> 6, lane = tid & 63, g = lane >> 4, l15 = lane & 15;
  int wr = wave >> 1, wc = wave & 1;

  int wg = blockIdx.x;
  int cpx = gridDim.x >> 3;
  int wg2 = (wg & 7) * cpx + (wg >> 3);
  int bx = wg2 % nbx, by = wg2 / nbx;
  int m0 = by * 128, n0 = bx * 128;

  int srow = tid >> 3;
  int cc = (tid & 7) ^ ((tid >> 3) & 7);
  const __bf16* Ag = A + (size_t)(m0 + srow) * K + cc * 8;
  const __bf16* Bg = BT + (size_t)(n0 + srow) * K + cc * 8;

  auto stage = [&](int kt, int bf) {
#pragma unroll
    for (int i = 0; i < 4; i++) {
      gload_lds16(Ag + (size_t)(i * 32) * K + kt * 64, &Asm[bf][wave * 512 + i * 2048]);
      gload_lds16(Bg + (size_t)(i * 32) * K + kt * 64, &Bsm[bf][wave * 512 + i * 2048]);
    }
  };

  f32x4 zz = {0.0f, 0.0f, 0.0f, 0.0f};
  f32x4 acc[4][4];
#pragma unroll
  for (int m = 0; m < 4; m++)
#pragma unroll
    for (int n = 0; n < 4; n++) acc[m][n] = zz;

  int nk = K >> 6;
  int swr = l15 & 7;

  stage(0, 0);
  __syncthreads();

  int cur = 0;
  for (int kt = 0; kt < nk; kt++) {
    if (kt + 1 < nk) stage(kt + 1, cur ^ 1);  // async, overlaps compute below
#pragma unroll
    for (int ks = 0; ks < 2; ks++) {
      bf16x8 af[4], bfr[4];
#pragma unroll
      for (int m = 0; m < 4; m++) {
        int row = wr * 64 + m * 16 + l15;
        af[m] = *(const bf16x8*)&Asm[cur][row * 64 + ((ks * 4 + g) ^ swr) * 8];
      }
#pragma unroll
      for (int n = 0; n < 4; n++) {
        int row = wc * 64 + n * 16 + l15;
        bfr[n] = *(const bf16x8*)&Bsm[cur][row * 64 + ((ks * 4 + g) ^ swr) * 8];
      }
#pragma unroll
      for (int m = 0; m < 4; m++)
#pragma unroll
        for (int n = 0; n < 4; n++)
          acc[m][n] = __builtin_amdgcn_mfma_f32_16x16x32_bf16(af[m], bfr[n], acc[m][n], 0, 0, 0);
    }
    __syncthreads();  // reads of cur done; kt+1 DMA drained
    cur ^= 1;
  }
#pragma unroll
  for (int n = 0; n < 4; n++) {
    int gcol = n0 + wc * 64 + n * 16 + l15;
    float bv = bias[gcol];
#pragma unroll
    for (int m = 0; m < 4; m++) {
      int grow0 = m0 + wr * 64 + m * 16 + g * 4;
      float v0 = acc[m][n][0] + bv, v1 = acc[m][n][1] + bv;
      float v2 = acc[m][n][2] + bv, v3 = acc[m][n][3] + bv;
      if (gcol < 2 * D_) {
        Cout[(size_t)(grow0 + 0) * N + gcol] = (__bf16)v0;
        Cout[(size_t)(grow0 + 1) * N + gcol] = (__bf16)v1;
        Cout[(size_t)(grow0 + 2) * N + gcol] = (__bf16)v2;
        Cout[(size_t)(grow0 + 3) * N + gcol] = (__bf16)v3;
      } else {
        // V -> VT[bh][d][t], t = 4 consecutive rows -> one bf16x4 store
        int hh = (gcol - 2 * D_) >> 6, dd = (gcol - 2 * D_) & 63;
        int bb = grow0 >> 10, tt = grow0 & 1023;
        bf16x4 sv = {(__bf16)v0, (__bf16)v1, (__bf16)v2, (__bf16)v3};
        *(bf16x4*)&VT[((size_t)(bb * NH + hh) * HD + dd) * T_ + tt] = sv;
      }
    }
  }
}

// ---------------- proj GEMM: 128x64 tile, 4 waves (1x row-split) ----------------
// grid = 64*12 = 768 = EXACTLY 3 blocks/CU (perfect balance). LDS 48KB dbuf
// -> 3 resident -> 12 waves/CU. Wave owns 32 rows x 64 cols: acc[2][4].
__global__ __launch_bounds__(256) void gemm_proj(const __bf16* __restrict__ A,
                                                 const __bf16* __restrict__ BT,
                                                 const float* __restrict__ bias,
                                                 float* __restrict__ Cout,
                                                 int M, int N, int K, int nbx) {
  __shared__ __align__(16) __bf16 Asm[2][128 * 64];
  __shared__ __align__(16) __bf16 Bsm[2][64 * 64];
  int tid = threadIdx.x;
  int wave = tid >> 6, lane = tid & 63, g = lane >> 4, l15 = lane & 15;

  int wg = blockIdx.x;
  int cpx = gridDim.x >> 3;
  int wg2 = (wg & 7) * cpx + (wg >> 3);
  int bx = wg2 % nbx, by = wg2 / nbx;
  int m0 = by * 128, n0 = bx * 64;

  int srow = tid >> 3;
  int cc = (tid & 7) ^ ((tid >> 3) & 7);
  const __bf16* Ag = A + (size_t)(m0 + srow) * K + cc * 8;
  const __bf16* Bg = BT + (size_t)(n0 + srow) * K + cc * 8;

  auto stage = [&](int kt, int bf) {
#pragma unroll
    for (int i = 0; i < 4; i++)
      gload_lds16(Ag + (size_t)(i * 32) * K + kt * 64, &Asm[bf][wave * 512 + i * 2048]);
#pragma unroll
    for (int i = 0; i < 2; i++)
      gload_lds16(Bg + (size_t)(i * 32) * K + kt * 64, &Bsm[bf][wave * 512 + i * 2048]);
  };

  f32x4 zz = {0.0f, 0.0f, 0.0f, 0.0f};
  f32x4 acc[2][4];
#pragma unroll
  for (int m = 0; m < 2; m++)
#pragma unroll
    for (int n = 0; n < 4; n++) acc[m][n] = zz;

  int nk = K >> 6;
  int swr = l15 & 7;

  stage(0, 0);
  __syncthreads();

  int cur = 0;
  for (int kt = 0; kt < nk; kt++) {
    if (kt + 1 < nk) stage(kt + 1, cur ^ 1);
#pragma unroll
    for (int ks = 0; ks < 2; ks++) {
      bf16x8 af[2], bfr[4];
#pragma unroll
      for (int m = 0; m < 2; m++) {
        int row = wave * 32 + m * 16 + l15;
        af[m] = *(const bf16x8*)&Asm[cur][row * 64 + ((ks * 4 + g) ^ swr) * 8];
      }
#pragma unroll
      for (int n = 0; n < 4; n++) {
        int row = n * 16 + l15;
        bfr[n] = *(const bf16x8*)&Bsm[cur][row * 64 + ((ks * 4 + g) ^ swr) * 8];
      }
#pragma unroll
      for (int m = 0; m < 2; m++)
#pragma unroll
        for (int n = 0; n < 4; n++)
          acc[m][n] = __builtin_amdgcn_mfma_f32_16x16x32_bf16(af[m], bfr[n], acc[m][n], 0, 0, 0);
    }
    __syncthreads();
    cur ^= 1;
  }
#pragma unroll
  for (int n = 0; n < 4; n++) {
    int gcol = n0 + n * 16 + l15;
    float bv = bias[gcol];
#pragma unroll
    for (int m = 0; m < 2; m++) {
      int grow0 = m0 + wave * 32 + m * 16 + g * 4;
#pragma unroll
      for (int r = 0; r < 4; r++)
        Cout[(size_t)(grow0 + r) * N + gcol] = acc[m][n][r] + bv;
    }
  }
}

// ---------------- causal flash attention (r13/r16 best-measured, reverted from r17) ----------------
#define SCL 0.1803368801111204f  // 0.125 * log2(e)

__global__ __launch_bounds__(256, 4) void attn_kernel(const __bf16* __restrict__ qkv,
                                                      const __bf16* __restrict__ VT,
                                                      __bf16* __restrict__ attn_out) {
  __shared__ __align__(16) __bf16 sm[2][2][4096];  // [buf][0=K,1=V][64x64]
  int tid = threadIdx.x;
  int wave = tid >> 6, lane = tid & 63, g = lane >> 4, l15 = lane & 15;
  int bh = blockIdx.x;
  int b = bh / NH, h = bh % NH;
  int qb = 15 - blockIdx.y;  // heavy first
  int q0w = qb * 64 + wave * 16;
  int nkt = qb + 1;
  int s0 = (bh + qb) % nkt;

  int kr = tid >> 3, cc = (tid & 7) ^ ((tid >> 3) & 7);
  const __bf16* Kst = qkv + (size_t)(b * T_ + kr) * (3 * D_) + D_ + h * HD + cc * 8;
  const __bf16* Vst = VT + ((size_t)bh * HD + kr) * T_ + cc * 8;
  __bf16* ldsK0 = &sm[0][0][wave * 512];
  __bf16* ldsV0 = &sm[0][1][wave * 512];
  __bf16* ldsK1 = &sm[1][0][wave * 512];
  __bf16* ldsV1 = &sm[1][1][wave * 512];

  auto stage = [&](int t, int bf) {
    size_t ko = (size_t)(t * 64) * (3 * D_);
    int vo = t * 64;
    __bf16* lk = bf ? ldsK1 : ldsK0;
    __bf16* lv = bf ? ldsV1 : ldsV0;
    gload_lds16(Kst + ko, lk);
    gload_lds16(Kst + ko + (size_t)32 * (3 * D_), lk + 2048);
    gload_lds16(Vst + vo, lv);
    gload_lds16(Vst + vo + 32 * T_, lv + 2048);
  };

  const __bf16* Qp = qkv + (size_t)(b * T_ + q0w + l15) * (3 * D_) + h * HD;
  bf16x8 qlo = *(const bf16x8*)(Qp + g * 8);
  bf16x8 qhi = *(const bf16x8*)(Qp + 32 + g * 8);

  f32x4 zz = {0.0f, 0.0f, 0.0f, 0.0f};
  f32x4 o0 = zz, o1 = zz, o2 = zz, o3 = zz;
  float m = -1e30f, l = 0.0f;
  int sw = l15 & 7;
  int clo = (g ^ sw) * 8;
  int chi = ((4 + g) ^ sw) * 8;

  stage(s0, 0);
  __syncthreads();

  int cur = 0;
  for (int i = 0; i < nkt; i++) {
    int kt = s0 + i;
    if (kt >= nkt) kt -= nkt;
    if (i + 1 < nkt) stage(kt + 1 == nkt ? 0 : kt + 1, cur ^ 1);

    const __bf16* Kb = &sm[cur][0][0];
    f32x4 s[4];
    __builtin_amdgcn_s_setprio(1);
#pragma unroll
    for (int kg = 0; kg < 4; kg++) {
      int rb = (kg * 16 + l15) * 64;
      bf16x8 kf = *(const bf16x8*)(Kb + rb + clo);
      bf16x8 kh = *(const bf16x8*)(Kb + rb + chi);
      s[kg] = mfma32(kf, qlo, zz);
      s[kg] = mfma32(kh, qhi, s[kg]);
    }
    __builtin_amdgcn_s_setprio(0);

    float v[16];
#pragma unroll
    for (int kg = 0; kg < 4; kg++)
#pragma unroll
      for (int r = 0; r < 4; r++) v[kg * 4 + r] = s[kg][r] * SCL;
    if (kt == qb) {
      int thr = wave * 16 + l15;
#pragma unroll
      for (int kg = 0; kg < 4; kg++)
#pragma unroll
        for (int r = 0; r < 4; r++)
          if (kg * 16 + g * 4 + r > thr) v[kg * 4 + r] = -1e30f;
    }
    float m0a = fmaxf(fmaxf(v[0], v[1]), fmaxf(v[2], v[3]));
    float m1a = fmaxf(fmaxf(v[4], v[5]), fmaxf(v[6], v[7]));
    float m2a = fmaxf(fmaxf(v[8], v[9]), fmaxf(v[10], v[11]));
    float m3a = fmaxf(fmaxf(v[12], v[13]), fmaxf(v[14], v[15]));
    float mx = fmaxf(fmaxf(m0a, m1a), fmaxf(m2a, m3a));
    mx = fmaxf(mx, __shfl_xor(mx, 16));
    mx = fmaxf(mx, __shfl_xor(mx, 32));
    if (!__all(mx <= m + 8.0f)) {  // T13 defer-max
      float mnew = fmaxf(m, mx);
      float corr = fast_exp2(m - mnew);
      o0 *= corr; o1 *= corr; o2 *= corr; o3 *= corr;
      l *= corr;
      m = mnew;
    }
    float p[16], sum = 0.0f;
#pragma unroll
    for (int i2 = 0; i2 < 16; i2++) { p[i2] = fast_exp2(v[i2] - m); sum += p[i2]; }
    sum += __shfl_xor(sum, 16);
    sum += __shfl_xor(sum, 32);
    l += sum;
    bf16x4 pk[4];
#pragma unroll
    for (int kg = 0; kg < 4; kg++) {
      pk[kg][0] = (__bf16)p[kg * 4 + 0];
      pk[kg][1] = (__bf16)p[kg * 4 + 1];
      pk[kg][2] = (__bf16)p[kg * 4 + 2];
      pk[kg][3] = (__bf16)p[kg * 4 + 3];
    }

    const __bf16* Vb = &sm[cur][1][0];
    int vhalf = (g & 1) * 4;
    int vc = g >> 1;
    __builtin_amdgcn_s_setprio(1);
#pragma unroll
    for (int dq = 0; dq < 4; dq++) {
      int drow = (dq * 16 + l15) * 64;
#pragma unroll
      for (int ks = 0; ks < 4; ks++) {
        bf16x4 vf = *(const bf16x4*)(Vb + drow + ((ks * 2 + vc) ^ sw) * 8 + vhalf);
        f32x4* op = (dq == 0) ? &o0 : (dq == 1) ? &o1 : (dq == 2) ? &o2 : &o3;
        *op = mfma16(vf, pk[ks], *op);
      }
    }
    __builtin_amdgcn_s_setprio(0);

    __syncthreads();
    cur ^= 1;
  }

  float invl = 1.0f / l;
  __bf16* outp = attn_out + (size_t)(b * T_ + q0w + l15) * D_ + h * HD + g * 4;
  bf16x4 t0 = {(__bf16)(o0[0] * invl), (__bf16)(o0[1] * invl), (__bf16)(o0[2] * invl), (__bf16)(o0[3] * invl)};
  bf16x4 t1 = {(__bf16)(o1[0] * invl), (__bf16)(o1[1] * invl), (__bf16)(o1[2] * invl), (__bf16)(o1[3] * invl)};
  bf16x4 t2 = {(__bf16)(o2[0] * invl), (__bf16)(o2[1] * invl), (__bf16)(o2[2] * invl), (__bf16)(o2[3] * invl)};
  bf16x4 t3 = {(__bf16)(o3[0] * invl), (__bf16)(o3[1] * invl), (__bf16)(o3[2] * invl), (__bf16)(o3[3] * invl)};
  *(bf16x4*)(outp) = t0;
  *(bf16x4*)(outp + 16) = t1;
  *(bf16x4*)(outp + 32) = t2;
  *(bf16x4*)(outp + 48) = t3;
}

extern "C" void kernel_launch(void* const* d_in, const int* in_sizes, int n_in,
                              void* d_out, int out_size, void* d_ws, size_t ws_size,
                              hipStream_t stream) {
  (void)in_sizes; (void)n_in; (void)out_size; (void)ws_size;
  const float* x = (const float*)d_in[0];
  const float* W_attn = (const float*)d_in[1];
  const float* b_attn = (const float*)d_in[2];
  const float* W_proj = (const float*)d_in[3];
  const float* b_proj = (const float*)d_in[4];

  char* ws = (char*)d_ws;
  __bf16* xb  = (__bf16*)(ws + 0);          // 8192*768*2        = 12,582,912
  __bf16* WaT = (__bf16*)(ws + 12582912);   // 2304*768*2        =  3,538,944
  __bf16* WpT = (__bf16*)(ws + 16121856);   // 768*768*2         =  1,179,648
  __bf16* qkv = (__bf16*)(ws + 17301504);   // 8192*2304*2       = 37,748,736
  __bf16* VTb = (__bf16*)(ws + 55050240);   // 96*64*1024*2      = 12,582,912
  __bf16* att = (__bf16*)(ws + 67633152);   // 8192*768*2        = 12,582,912

  prep_kernel<<<dim3(5376), 256, 0, stream>>>(x, xb, W_attn, WaT, W_proj, WpT);
  gemm_qkv<<<dim3(1152), 256, 0, stream>>>(xb, WaT, b_attn, qkv, VTb, 8192, 2304, 768, 18);
  attn_kernel<<<dim3(96, 16), 256, 0, stream>>>(qkv, VTb, att);
  gemm_proj<<<dim3(768), 256, 0, stream>>>(att, WpT, b_proj, (float*)d_out, 8192, 768, 768, 12);
}

// Round 19
// 105.162 us; speedup vs baseline: 1.1052x; 1.0623x over previous
//
#include <hip/hip_runtime.h>
#include <hip/hip_bf16.h>

// GPT2 attention: B=8, T=1024, D=768, H=12, hd=64. fp32 in/out, bf16 MFMA compute.
#define B_ 8
#define T_ 1024
#define D_ 768
#define NH 12
#define HD 64

typedef __bf16 bf16x8 __attribute__((ext_vector_type(8)));
typedef __bf16 bf16x4 __attribute__((ext_vector_type(4)));
typedef float f32x4 __attribute__((ext_vector_type(4)));
typedef short s16x4 __attribute__((ext_vector_type(4)));

__device__ __forceinline__ float fast_exp2(float x) {
  return __builtin_amdgcn_exp2f(x);
}

__device__ __forceinline__ f32x4 mfma32(bf16x8 a, bf16x8 b, f32x4 c) {
  return __builtin_amdgcn_mfma_f32_16x16x32_bf16(a, b, c, 0, 0, 0);
}

__device__ __forceinline__ f32x4 mfma16(bf16x4 a, bf16x4 b, f32x4 c) {
  union U { bf16x4 h; s16x4 s; };
  U ua; ua.h = a;
  U ub; ub.h = b;
  return __builtin_amdgcn_mfma_f32_16x16x16bf16_1k(ua.s, ub.s, c, 0, 0, 0);
}

// async global->LDS, 16B per lane; LDS dest = wave-uniform base + lane*16
__device__ __forceinline__ void gload_lds16(const void* g, void* l) {
  __builtin_amdgcn_global_load_lds((const __attribute__((address_space(1))) unsigned int*)g,
                                   (__attribute__((address_space(3))) unsigned int*)l, 16, 0, 0);
}

// ---------------- merged prep: x->bf16 + both W transposes (one launch) ----------------
__global__ void prep_kernel(const float* __restrict__ x, __bf16* __restrict__ xb,
                            const float* __restrict__ W_attn, __bf16* __restrict__ WaT,
                            const float* __restrict__ W_proj, __bf16* __restrict__ WpT) {
  int bid = blockIdx.x;
  int tid = threadIdx.x;
  if (bid < 3072) {
    int i = bid * 256 + tid;
    const float4* xf = (const float4*)x;
    float4 a = xf[i * 2], b = xf[i * 2 + 1];
    bf16x8 v;
    v[0] = (__bf16)a.x; v[1] = (__bf16)a.y; v[2] = (__bf16)a.z; v[3] = (__bf16)a.w;
    v[4] = (__bf16)b.x; v[5] = (__bf16)b.y; v[6] = (__bf16)b.z; v[7] = (__bf16)b.w;
    *(bf16x8*)&xb[(size_t)i * 8] = v;
    return;
  }
  __shared__ float tile[32][33];
  const float* W;
  __bf16* WT;
  int K = 768, N, n0, k0;
  if (bid < 4800) {
    int i = bid - 3072;
    W = W_attn; WT = WaT; N = 2304;
    n0 = (i % 72) * 32; k0 = (i / 72) * 32;
  } else {
    int i = bid - 4800;
    W = W_proj; WT = WpT; N = 768;
    n0 = (i % 24) * 32; k0 = (i / 24) * 32;
  }
  int col = tid & 31, r0 = tid >> 5;
#pragma unroll
  for (int p = 0; p < 4; p++) {
    int r = r0 + p * 8;
    tile[r][col] = W[(size_t)(k0 + r) * N + n0 + col];
  }
  __syncthreads();
#pragma unroll
  for (int p = 0; p < 4; p++) {
    int r = r0 + p * 8;
    WT[(size_t)(n0 + r) * K + k0 + col] = (__bf16)tile[col][r];
  }
}

// ---------------- QKV GEMM: 128x64 tile (proj-proven shape), 3 blocks/CU ----------------
// r18 lesson: at 128x128 dbuf (64KB) only 2 blocks/CU resident — the 2-phase
// barrier drain under-hides (m114 mechanism needs ~3 blocks/CU). This kernel
// is the gemm_proj loop (measured win at r15->r16) with the qkv epilogue:
// 48KB LDS dbuf -> 3 blocks/CU, grid 64x36 = 2304 = exactly 3 full rounds.
// Per-step: 6 gload issues, wave = 32 rows x 64 cols (acc[2][4]).
// Both-sides XOR swizzle -> 0 conflicts. T1 XCD swizzle (grid%8==0).
// Epilogue: Q,K -> qkv; V -> VT[bh][d][t] (vtrepack fused).
__global__ __launch_bounds__(256) void gemm_qkv(const __bf16* __restrict__ A,
                                                const __bf16* __restrict__ BT,
                                                const float* __restrict__ bias,
                                                __bf16* __restrict__ Cout,
                                                __bf16* __restrict__ VT,
                                                int M, int N, int K, int nbx) {
  __shared__ __align__(16) __bf16 Asm[2][128 * 64];
  __shared__ __align__(16) __bf16 Bsm[2][64 * 64];
  int tid = threadIdx.x;
  int wave = tid >> 6, lane = tid & 63, g = lane >> 4, l15 = lane & 15;

  int wg = blockIdx.x;
  int cpx = gridDim.x >> 3;
  int wg2 = (wg & 7) * cpx + (wg >> 3);
  int bx = wg2 % nbx, by = wg2 / nbx;
  int m0 = by * 128, n0 = bx * 64;

  int srow = tid >> 3;
  int cc = (tid & 7) ^ ((tid >> 3) & 7);
  const __bf16* Ag = A + (size_t)(m0 + srow) * K + cc * 8;
  const __bf16* Bg = BT + (size_t)(n0 + srow) * K + cc * 8;

  auto stage = [&](int kt, int bf) {
#pragma unroll
    for (int i = 0; i < 4; i++)
      gload_lds16(Ag + (size_t)(i * 32) * K + kt * 64, &Asm[bf][wave * 512 + i * 2048]);
#pragma unroll
    for (int i = 0; i < 2; i++)
      gload_lds16(Bg + (size_t)(i * 32) * K + kt * 64, &Bsm[bf][wave * 512 + i * 2048]);
  };

  f32x4 zz = {0.0f, 0.0f, 0.0f, 0.0f};
  f32x4 acc[2][4];
#pragma unroll
  for (int m = 0; m < 2; m++)
#pragma unroll
    for (int n = 0; n < 4; n++) acc[m][n] = zz;

  int nk = K >> 6;
  int swr = l15 & 7;

  stage(0, 0);
  __syncthreads();

  int cur = 0;
  for (int kt = 0; kt < nk; kt++) {
    if (kt + 1 < nk) stage(kt + 1, cur ^ 1);  // async, overlaps compute below
#pragma unroll
    for (int ks = 0; ks < 2; ks++) {
      bf16x8 af[2], bfr[4];
#pragma unroll
      for (int m = 0; m < 2; m++) {
        int row = wave * 32 + m * 16 + l15;
        af[m] = *(const bf16x8*)&Asm[cur][row * 64 + ((ks * 4 + g) ^ swr) * 8];
      }
#pragma unroll
      for (int n = 0; n < 4; n++) {
        int row = n * 16 + l15;
        bfr[n] = *(const bf16x8*)&Bsm[cur][row * 64 + ((ks * 4 + g) ^ swr) * 8];
      }
#pragma unroll
      for (int m = 0; m < 2; m++)
#pragma unroll
        for (int n = 0; n < 4; n++)
          acc[m][n] = __builtin_amdgcn_mfma_f32_16x16x32_bf16(af[m], bfr[n], acc[m][n], 0, 0, 0);
    }
    __syncthreads();  // reads of cur done; kt+1 DMA drained
    cur ^= 1;
  }
#pragma unroll
  for (int n = 0; n < 4; n++) {
    int gcol = n0 + n * 16 + l15;
    float bv = bias[gcol];
#pragma unroll
    for (int m = 0; m < 2; m++) {
      int grow0 = m0 + wave * 32 + m * 16 + g * 4;
      float v0 = acc[m][n][0] + bv, v1 = acc[m][n][1] + bv;
      float v2 = acc[m][n][2] + bv, v3 = acc[m][n][3] + bv;
      if (gcol < 2 * D_) {
        Cout[(size_t)(grow0 + 0) * N + gcol] = (__bf16)v0;
        Cout[(size_t)(grow0 + 1) * N + gcol] = (__bf16)v1;
        Cout[(size_t)(grow0 + 2) * N + gcol] = (__bf16)v2;
        Cout[(size_t)(grow0 + 3) * N + gcol] = (__bf16)v3;
      } else {
        // V -> VT[bh][d][t], t = 4 consecutive rows -> one bf16x4 store
        int hh = (gcol - 2 * D_) >> 6, dd = (gcol - 2 * D_) & 63;
        int bb = grow0 >> 10, tt = grow0 & 1023;
        bf16x4 sv = {(__bf16)v0, (__bf16)v1, (__bf16)v2, (__bf16)v3};
        *(bf16x4*)&VT[((size_t)(bb * NH + hh) * HD + dd) * T_ + tt] = sv;
      }
    }
  }
}

// ---------------- proj GEMM: 128x64 tile (r15, unchanged) ----------------
__global__ __launch_bounds__(256) void gemm_proj(const __bf16* __restrict__ A,
                                                 const __bf16* __restrict__ BT,
                                                 const float* __restrict__ bias,
                                                 float* __restrict__ Cout,
                                                 int M, int N, int K, int nbx) {
  __shared__ __align__(16) __bf16 Asm[2][128 * 64];
  __shared__ __align__(16) __bf16 Bsm[2][64 * 64];
  int tid = threadIdx.x;
  int wave = tid >> 6, lane = tid & 63, g = lane >> 4, l15 = lane & 15;

  int wg = blockIdx.x;
  int cpx = gridDim.x >> 3;
  int wg2 = (wg & 7) * cpx + (wg >> 3);
  int bx = wg2 % nbx, by = wg2 / nbx;
  int m0 = by * 128, n0 = bx * 64;

  int srow = tid >> 3;
  int cc = (tid & 7) ^ ((tid >> 3) & 7);
  const __bf16* Ag = A + (size_t)(m0 + srow) * K + cc * 8;
  const __bf16* Bg = BT + (size_t)(n0 + srow) * K + cc * 8;

  auto stage = [&](int kt, int bf) {
#pragma unroll
    for (int i = 0; i < 4; i++)
      gload_lds16(Ag + (size_t)(i * 32) * K + kt * 64, &Asm[bf][wave * 512 + i * 2048]);
#pragma unroll
    for (int i = 0; i < 2; i++)
      gload_lds16(Bg + (size_t)(i * 32) * K + kt * 64, &Bsm[bf][wave * 512 + i * 2048]);
  };

  f32x4 zz = {0.0f, 0.0f, 0.0f, 0.0f};
  f32x4 acc[2][4];
#pragma unroll
  for (int m = 0; m < 2; m++)
#pragma unroll
    for (int n = 0; n < 4; n++) acc[m][n] = zz;

  int nk = K >> 6;
  int swr = l15 & 7;

  stage(0, 0);
  __syncthreads();

  int cur = 0;
  for (int kt = 0; kt < nk; kt++) {
    if (kt + 1 < nk) stage(kt + 1, cur ^ 1);
#pragma unroll
    for (int ks = 0; ks < 2; ks++) {
      bf16x8 af[2], bfr[4];
#pragma unroll
      for (int m = 0; m < 2; m++) {
        int row = wave * 32 + m * 16 + l15;
        af[m] = *(const bf16x8*)&Asm[cur][row * 64 + ((ks * 4 + g) ^ swr) * 8];
      }
#pragma unroll
      for (int n = 0; n < 4; n++) {
        int row = n * 16 + l15;
        bfr[n] = *(const bf16x8*)&Bsm[cur][row * 64 + ((ks * 4 + g) ^ swr) * 8];
      }
#pragma unroll
      for (int m = 0; m < 2; m++)
#pragma unroll
        for (int n = 0; n < 4; n++)
          acc[m][n] = __builtin_amdgcn_mfma_f32_16x16x32_bf16(af[m], bfr[n], acc[m][n], 0, 0, 0);
    }
    __syncthreads();
    cur ^= 1;
  }
#pragma unroll
  for (int n = 0; n < 4; n++) {
    int gcol = n0 + n * 16 + l15;
    float bv = bias[gcol];
#pragma unroll
    for (int m = 0; m < 2; m++) {
      int grow0 = m0 + wave * 32 + m * 16 + g * 4;
#pragma unroll
      for (int r = 0; r < 4; r++)
        Cout[(size_t)(grow0 + r) * N + gcol] = acc[m][n][r] + bv;
    }
  }
}

// ---------------- causal flash attention (r13/r16 best-measured, unchanged) ----------------
#define SCL 0.1803368801111204f  // 0.125 * log2(e)

__global__ __launch_bounds__(256, 4) void attn_kernel(const __bf16* __restrict__ qkv,
                                                      const __bf16* __restrict__ VT,
                                                      __bf16* __restrict__ attn_out) {
  __shared__ __align__(16) __bf16 sm[2][2][4096];  // [buf][0=K,1=V][64x64]
  int tid = threadIdx.x;
  int wave = tid >> 6, lane = tid & 63, g = lane >> 4, l15 = lane & 15;
  int bh = blockIdx.x;
  int b = bh / NH, h = bh % NH;
  int qb = 15 - blockIdx.y;  // heavy first
  int q0w = qb * 64 + wave * 16;
  int nkt = qb + 1;
  int s0 = (bh + qb) % nkt;

  int kr = tid >> 3, cc = (tid & 7) ^ ((tid >> 3) & 7);
  const __bf16* Kst = qkv + (size_t)(b * T_ + kr) * (3 * D_) + D_ + h * HD + cc * 8;
  const __bf16* Vst = VT + ((size_t)bh * HD + kr) * T_ + cc * 8;
  __bf16* ldsK0 = &sm[0][0][wave * 512];
  __bf16* ldsV0 = &sm[0][1][wave * 512];
  __bf16* ldsK1 = &sm[1][0][wave * 512];
  __bf16* ldsV1 = &sm[1][1][wave * 512];

  auto stage = [&](int t, int bf) {
    size_t ko = (size_t)(t * 64) * (3 * D_);
    int vo = t * 64;
    __bf16* lk = bf ? ldsK1 : ldsK0;
    __bf16* lv = bf ? ldsV1 : ldsV0;
    gload_lds16(Kst + ko, lk);
    gload_lds16(Kst + ko + (size_t)32 * (3 * D_), lk + 2048);
    gload_lds16(Vst + vo, lv);
    gload_lds16(Vst + vo + 32 * T_, lv + 2048);
  };

  const __bf16* Qp = qkv + (size_t)(b * T_ + q0w + l15) * (3 * D_) + h * HD;
  bf16x8 qlo = *(const bf16x8*)(Qp + g * 8);
  bf16x8 qhi = *(const bf16x8*)(Qp + 32 + g * 8);

  f32x4 zz = {0.0f, 0.0f, 0.0f, 0.0f};
  f32x4 o0 = zz, o1 = zz, o2 = zz, o3 = zz;
  float m = -1e30f, l = 0.0f;
  int sw = l15 & 7;
  int clo = (g ^ sw) * 8;
  int chi = ((4 + g) ^ sw) * 8;

  stage(s0, 0);
  __syncthreads();

  int cur = 0;
  for (int i = 0; i < nkt; i++) {
    int kt = s0 + i;
    if (kt >= nkt) kt -= nkt;
    if (i + 1 < nkt) stage(kt + 1 == nkt ? 0 : kt + 1, cur ^ 1);

    const __bf16* Kb = &sm[cur][0][0];
    f32x4 s[4];
    __builtin_amdgcn_s_setprio(1);
#pragma unroll
    for (int kg = 0; kg < 4; kg++) {
      int rb = (kg * 16 + l15) * 64;
      bf16x8 kf = *(const bf16x8*)(Kb + rb + clo);
      bf16x8 kh = *(const bf16x8*)(Kb + rb + chi);
      s[kg] = mfma32(kf, qlo, zz);
      s[kg] = mfma32(kh, qhi, s[kg]);
    }
    __builtin_amdgcn_s_setprio(0);

    float v[16];
#pragma unroll
    for (int kg = 0; kg < 4; kg++)
#pragma unroll
      for (int r = 0; r < 4; r++) v[kg * 4 + r] = s[kg][r] * SCL;
    if (kt == qb) {
      int thr = wave * 16 + l15;
#pragma unroll
      for (int kg = 0; kg < 4; kg++)
#pragma unroll
        for (int r = 0; r < 4; r++)
          if (kg * 16 + g * 4 + r > thr) v[kg * 4 + r] = -1e30f;
    }
    float m0a = fmaxf(fmaxf(v[0], v[1]), fmaxf(v[2], v[3]));
    float m1a = fmaxf(fmaxf(v[4], v[5]), fmaxf(v[6], v[7]));
    float m2a = fmaxf(fmaxf(v[8], v[9]), fmaxf(v[10], v[11]));
    float m3a = fmaxf(fmaxf(v[12], v[13]), fmaxf(v[14], v[15]));
    float mx = fmaxf(fmaxf(m0a, m1a), fmaxf(m2a, m3a));
    mx = fmaxf(mx, __shfl_xor(mx, 16));
    mx = fmaxf(mx, __shfl_xor(mx, 32));
    if (!__all(mx <= m + 8.0f)) {  // T13 defer-max
      float mnew = fmaxf(m, mx);
      float corr = fast_exp2(m - mnew);
      o0 *= corr; o1 *= corr; o2 *= corr; o3 *= corr;
      l *= corr;
      m = mnew;
    }
    float p[16], sum = 0.0f;
#pragma unroll
    for (int i2 = 0; i2 < 16; i2++) { p[i2] = fast_exp2(v[i2] - m); sum += p[i2]; }
    sum += __shfl_xor(sum, 16);
    sum += __shfl_xor(sum, 32);
    l += sum;
    bf16x4 pk[4];
#pragma unroll
    for (int kg = 0; kg < 4; kg++) {
      pk[kg][0] = (__bf16)p[kg * 4 + 0];
      pk[kg][1] = (__bf16)p[kg * 4 + 1];
      pk[kg][2] = (__bf16)p[kg * 4 + 2];
      pk[kg][3] = (__bf16)p[kg * 4 + 3];
    }

    const __bf16* Vb = &sm[cur][1][0];
    int vhalf = (g & 1) * 4;
    int vc = g >> 1;
    __builtin_amdgcn_s_setprio(1);
#pragma unroll
    for (int dq = 0; dq < 4; dq++) {
      int drow = (dq * 16 + l15) * 64;
#pragma unroll
      for (int ks = 0; ks < 4; ks++) {
        bf16x4 vf = *(const bf16x4*)(Vb + drow + ((ks * 2 + vc) ^ sw) * 8 + vhalf);
        f32x4* op = (dq == 0) ? &o0 : (dq == 1) ? &o1 : (dq == 2) ? &o2 : &o3;
        *op = mfma16(vf, pk[ks], *op);
      }
    }
    __builtin_amdgcn_s_setprio(0);

    __syncthreads();
    cur ^= 1;
  }

  float invl = 1.0f / l;
  __bf16* outp = attn_out + (size_t)(b * T_ + q0w + l15) * D_ + h * HD + g * 4;
  bf16x4 t0 = {(__bf16)(o0[0] * invl), (__bf16)(o0[1] * invl), (__bf16)(o0[2] * invl), (__bf16)(o0[3] * invl)};
  bf16x4 t1 = {(__bf16)(o1[0] * invl), (__bf16)(o1[1] * invl), (__bf16)(o1[2] * invl), (__bf16)(o1[3] * invl)};
  bf16x4 t2 = {(__bf16)(o2[0] * invl), (__bf16)(o2[1] * invl), (__bf16)(o2[2] * invl), (__bf16)(o2[3] * invl)};
  bf16x4 t3 = {(__bf16)(o3[0] * invl), (__bf16)(o3[1] * invl), (__bf16)(o3[2] * invl), (__bf16)(o3[3] * invl)};
  *(bf16x4*)(outp) = t0;
  *(bf16x4*)(outp + 16) = t1;
  *(bf16x4*)(outp + 32) = t2;
  *(bf16x4*)(outp + 48) = t3;
}

extern "C" void kernel_launch(void* const* d_in, const int* in_sizes, int n_in,
                              void* d_out, int out_size, void* d_ws, size_t ws_size,
                              hipStream_t stream) {
  (void)in_sizes; (void)n_in; (void)out_size; (void)ws_size;
  const float* x = (const float*)d_in[0];
  const float* W_attn = (const float*)d_in[1];
  const float* b_attn = (const float*)d_in[2];
  const float* W_proj = (const float*)d_in[3];
  const float* b_proj = (const float*)d_in[4];

  char* ws = (char*)d_ws;
  __bf16* xb  = (__bf16*)(ws + 0);          // 8192*768*2        = 12,582,912
  __bf16* WaT = (__bf16*)(ws + 12582912);   // 2304*768*2        =  3,538,944
  __bf16* WpT = (__bf16*)(ws + 16121856);   // 768*768*2         =  1,179,648
  __bf16* qkv = (__bf16*)(ws + 17301504);   // 8192*2304*2       = 37,748,736
  __bf16* VTb = (__bf16*)(ws + 55050240);   // 96*64*1024*2      = 12,582,912
  __bf16* att = (__bf16*)(ws + 67633152);   // 8192*768*2        = 12,582,912

  prep_kernel<<<dim3(5376), 256, 0, stream>>>(x, xb, W_attn, WaT, W_proj, WpT);
  gemm_qkv<<<dim3(2304), 256, 0, stream>>>(xb, WaT, b_attn, qkv, VTb, 8192, 2304, 768, 36);
  attn_kernel<<<dim3(96, 16), 256, 0, stream>>>(qkv, VTb, att);
  gemm_proj<<<dim3(768), 256, 0, stream>>>(att, WpT, b_proj, (float*)d_out, 8192, 768, 768, 12);
}